// Round 12
// baseline (72.790 us; speedup 1.0000x reference)
//
#include <hip/hip_runtime.h>
#include <hip/hip_bf16.h>

#define NN 512
#define FIN 128
#define HH 4
#define DD 64
#define SW 68   // permuted/padded e-width: 17 groups x 4
// lrelu(z) = 0.6*z + 0.4*|z|; a.lrelu folded: 0.6*(a.zi+a.zj) + sum_g sgn_g*|azi+azj|

// ws layout (floats):
//  h_ws   [8][512][64]         262144  @ 0
//  azi_ws [8][512][68]         278528  @ 262144   (|a|-scaled, e-permuted, zi+Wcb)
//  azj_ws [8][512][68]         278528  @ 540672   (row-major, same permutation)
//  adi_ws [8][512]             4096    @ 819200   (0.6 * sum_e a*zi')
//  adj_ws [8][512]             4096    @ 823296
//  pacc   [16][8][512][64]     4194304 @ 827392
//  pm     [16][4096]           65536   @ 5021696
//  ps     [16][4096]           65536   @ 5087232

// ---------------------------------------------------------------------------
// proj (r5-validated structure): row-major azi/azj scatter. 512 blocks x 256.
// ---------------------------------------------------------------------------
__global__ __launch_bounds__(256) void proj_kernel(
    const float* __restrict__ x, const float* __restrict__ Wp,
    const float* __restrict__ bp, const float* __restrict__ Wc,
    const float* __restrict__ Wcb, const float* __restrict__ a,
    float* __restrict__ h_ws, float* __restrict__ azi_ws, float* __restrict__ azj_ws,
    float* __restrict__ adi_ws, float* __restrict__ adj_ws)
{
    int blk = blockIdx.x;
    int bh = blk >> 6;
    int n0 = (blk & 63) << 3;
    int b = bh >> 2, hh = bh & 3;

    __shared__ float xs[8 * FIN];
    __shared__ float hs[8][DD];
    __shared__ float Wcs[DD][2 * DD + 1];

    int t = threadIdx.x;

    ((float4*)xs)[t] = ((const float4*)(x + ((size_t)b * NN + n0) * FIN))[t];
    {
        const float4* wg = (const float4*)(Wc + (size_t)hh * DD * 2 * DD);
        #pragma unroll
        for (int k = 0; k < 8; ++k) {
            int idx = t + 256 * k;
            int r = idx >> 5, c4 = (idx & 31) * 4;
            float4 v = wg[idx];
            Wcs[r][c4] = v.x; Wcs[r][c4 + 1] = v.y;
            Wcs[r][c4 + 2] = v.z; Wcs[r][c4 + 3] = v.w;
        }
    }
    __syncthreads();

    int e = t & 63, w = t >> 6;            // rows w, w+4
    const float* Wph = Wp + (size_t)hh * FIN * DD;
    float bpv = bp[hh * DD + e];
    float acc0 = bpv, acc1 = bpv;
    #pragma unroll 8
    for (int i = 0; i < FIN; ++i) {
        float wv = Wph[i * DD + e];
        acc0 = fmaf(xs[w * FIN + i], wv, acc0);
        acc1 = fmaf(xs[(w + 4) * FIN + i], wv, acc1);
    }
    hs[w][e] = acc0; hs[w + 4][e] = acc1;
    float* hg = h_ws + ((size_t)bh * NN + n0) * DD;
    hg[w * DD + e] = acc0; hg[(w + 4) * DD + e] = acc1;
    __syncthreads();

    float zb = Wcb[hh * DD + e];
    float zi0 = zb, zi1 = zb, zj0 = 0.f, zj1 = 0.f;
    #pragma unroll 8
    for (int d2 = 0; d2 < DD; ++d2) {
        float w1 = Wcs[e][d2];
        float w2 = Wcs[e][DD + d2];
        float h0 = hs[w][d2], h1 = hs[w + 4][d2];
        zi0 = fmaf(h0, w1, zi0); zi1 = fmaf(h1, w1, zi1);
        zj0 = fmaf(h0, w2, zj0); zj1 = fmaf(h1, w2, zj1);
    }

    float av = a[hh * DD + e];
    float p0 = av * zi0, p1 = av * zi1, q0 = av * zj0, q1 = av * zj1;
    #pragma unroll
    for (int off = 32; off; off >>= 1) {
        p0 += __shfl_xor(p0, off); p1 += __shfl_xor(p1, off);
        q0 += __shfl_xor(q0, off); q1 += __shfl_xor(q1, off);
    }
    if (e == 0) {
        adi_ws[bh * NN + n0 + w]     = 0.6f * p0;
        adi_ws[bh * NN + n0 + w + 4] = 0.6f * p1;
        adj_ws[bh * NN + n0 + w]     = 0.6f * q0;
        adj_ws[bh * NN + n0 + w + 4] = 0.6f * q1;
    }

    unsigned long long mask = __ballot(av >= 0.f);
    int np = __popcll(mask);
    int GP = (np + 3) >> 2;
    int below = __popcll(mask & ((1ull << e) - 1ull));
    int slot = (av >= 0.f) ? below : (4 * GP + (e - below));
    float pav = __builtin_fabsf(av);

    float* azib = azi_ws + ((size_t)bh * NN + n0) * SW;
    float* azjb = azj_ws + ((size_t)bh * NN + n0) * SW;
    azib[w * SW + slot]       = pav * zi0;
    azib[(w + 4) * SW + slot] = pav * zi1;
    azjb[w * SW + slot]       = pav * zj0;
    azjb[(w + 4) * SW + slot] = pav * zj1;
    int p1c = 4 * GP - np;
    if (e < 4) {
        int psl = (e < p1c) ? (np + e) : (4 * GP + 64 - np + (e - p1c));
        azib[w * SW + psl] = 0.f; azib[(w + 4) * SW + psl] = 0.f;
        azjb[w * SW + psl] = 0.f; azjb[(w + 4) * SW + psl] = 0.f;
    }
}

// ---------------------------------------------------------------------------
// attn4 ("register-file attention"): lane = i. 1-wave blocks, [64 i][32 j].
// grid = 8bh x 8is x 16js = 1024 blocks x 64 thr. azj/h via SCALAR loads;
// softmax per-lane in regs (no shfl, no LDS); LDS only for output transpose.
// ---------------------------------------------------------------------------
__global__ __launch_bounds__(64) void attn4(
    const float* __restrict__ h_ws, const float* __restrict__ azi_ws,
    const float* __restrict__ azj_ws, const float* __restrict__ adi_ws,
    const float* __restrict__ adj_ws, const float* __restrict__ a,
    float* __restrict__ pacc, float* __restrict__ pm, float* __restrict__ ps)
{
    int blk = blockIdx.x;
    int js = blk & 15, is_ = (blk >> 4) & 7, bh = blk >> 7;
    int i0 = is_ << 6, j0 = js << 5, hh = bh & 3;
    int lane = threadIdx.x;

    __shared__ float tr[64 * 65];      // 16.6 KB, output transpose only

    // azi row for this lane's i (L2-resident after first istrip)
    float4 azi4[17];
    {
        const float4* zr = (const float4*)(azi_ws + ((size_t)bh * NN + i0 + lane) * SW);
        #pragma unroll
        for (int k = 0; k < 17; ++k) azi4[k] = zr[k];
    }
    float adiv = adi_ws[bh * NN + i0 + lane];

    float av_e = a[hh * DD + lane];
    unsigned long long mask = __ballot(av_e >= 0.f);
    int GP = (__popcll(mask) + 3) >> 2;

    const float* ajbase = azj_ws + ((size_t)bh * NN + j0) * SW;   // uniform
    const float* adjb   = adj_ws + bh * NN + j0;                  // uniform
    float p[32];

    // ---- scores: pure VALU; azj via scalar (SMEM) loads ----
    #pragma unroll
    for (int j = 0; j < 32; ++j) {
        const float4* aj4 = (const float4*)(ajbase + j * SW);
        float c0 = 0.f, c1 = 0.f, c2 = 0.f, c3 = 0.f;
        #pragma unroll
        for (int k = 0; k < 17; ++k) {
            float4 s4 = aj4[k];                     // s_load_dwordx4
            float sg = (k < GP) ? 0.4f : -0.4f;     // s_cselect
            c0 = fmaf(sg, __builtin_fabsf(azi4[k].x + s4.x), c0);
            c1 = fmaf(sg, __builtin_fabsf(azi4[k].y + s4.y), c1);
            c2 = fmaf(sg, __builtin_fabsf(azi4[k].z + s4.z), c2);
            c3 = fmaf(sg, __builtin_fabsf(azi4[k].w + s4.w), c3);
        }
        p[j] = adiv + adjb[j] + ((c0 + c1) + (c2 + c3));
    }

    // ---- per-lane softmax partial over 32 registers (no shfl) ----
    float m = p[0];
    #pragma unroll
    for (int j = 1; j < 32; ++j) m = fmaxf(m, p[j]);
    float s = 0.f;
    #pragma unroll
    for (int j = 0; j < 32; ++j) { p[j] = __expf(p[j] - m); s += p[j]; }
    pm[js * 4096 + bh * NN + i0 + lane] = m;
    ps[js * 4096 + bh * NN + i0 + lane] = s;

    // ---- PV: pure VALU; h via scalar loads ----
    float4 acc4[16];
    #pragma unroll
    for (int k = 0; k < 16; ++k) acc4[k] = make_float4(0.f, 0.f, 0.f, 0.f);
    const float* hb = h_ws + ((size_t)bh * NN + j0) * DD;          // uniform
    #pragma unroll
    for (int j = 0; j < 32; ++j) {
        const float4* h4 = (const float4*)(hb + j * DD);
        float pj = p[j];
        #pragma unroll
        for (int k = 0; k < 16; ++k) {
            float4 hv = h4[k];                      // s_load_dwordx4
            acc4[k].x = fmaf(pj, hv.x, acc4[k].x);
            acc4[k].y = fmaf(pj, hv.y, acc4[k].y);
            acc4[k].z = fmaf(pj, hv.z, acc4[k].z);
            acc4[k].w = fmaf(pj, hv.w, acc4[k].w);
        }
    }

    // ---- epilogue: transpose via padded LDS, coalesced store ----
    #pragma unroll
    for (int k = 0; k < 16; ++k) {
        tr[lane * 65 + 4 * k + 0] = acc4[k].x;
        tr[lane * 65 + 4 * k + 1] = acc4[k].y;
        tr[lane * 65 + 4 * k + 2] = acc4[k].z;
        tr[lane * 65 + 4 * k + 3] = acc4[k].w;
    }
    __syncthreads();   // single wave: compiles to waitcnt only
    float* pb = pacc + ((size_t)(js * 8 + bh) * NN + i0) * DD + lane;
    #pragma unroll
    for (int i = 0; i < 64; ++i)
        pb[(size_t)i * DD] = tr[i * 65 + lane];
}

// ---------------------------------------------------------------------------
// combine 16 j-splits + bias. grid = 1024 x 256.
// ---------------------------------------------------------------------------
__global__ __launch_bounds__(256) void combine_kernel(
    const float* __restrict__ pacc, const float* __restrict__ pm,
    const float* __restrict__ ps, const float* __restrict__ bias_param,
    float* __restrict__ out)
{
    int tid = blockIdx.x * 256 + threadIdx.x;
    int d = tid & 63;
    int row = tid >> 6;                 // bh*512 + n, 4096 rows
    int bh = row >> 9, n = row & 511;
    int b = bh >> 2, hh = bh & 3;
    float mv[16];
    float m = -1e30f;
    #pragma unroll
    for (int p = 0; p < 16; ++p) { mv[p] = pm[p * 4096 + row]; m = fmaxf(m, mv[p]); }
    float denom = 0.f, acc = 0.f;
    #pragma unroll
    for (int p = 0; p < 16; ++p) {
        float wgt = __expf(mv[p] - m);
        denom = fmaf(ps[p * 4096 + row], wgt, denom);
        acc = fmaf(pacc[(size_t)p * 262144 + (size_t)row * 64 + d], wgt, acc);
    }
    out[((size_t)b * NN + n) * (HH * DD) + hh * DD + d] =
        acc / denom + bias_param[hh * DD + d];
}

extern "C" void kernel_launch(void* const* d_in, const int* in_sizes, int n_in,
                              void* d_out, int out_size, void* d_ws, size_t ws_size,
                              hipStream_t stream) {
    const float* x    = (const float*)d_in[0];
    const float* Wp   = (const float*)d_in[1];
    const float* bp   = (const float*)d_in[2];
    const float* Wc   = (const float*)d_in[3];
    const float* Wcb  = (const float*)d_in[4];
    const float* a    = (const float*)d_in[5];
    const float* bpar = (const float*)d_in[6];
    float* out = (float*)d_out;

    float* ws     = (float*)d_ws;
    float* h_ws   = ws;
    float* azi_ws = ws + 262144;
    float* azj_ws = ws + 540672;
    float* adi_ws = ws + 819200;
    float* adj_ws = ws + 823296;
    float* pacc   = ws + 827392;
    float* pm     = ws + 5021696;
    float* ps     = ws + 5087232;

    proj_kernel<<<dim3(512), dim3(256), 0, stream>>>(
        x, Wp, bp, Wc, Wcb, a, h_ws, azi_ws, azj_ws, adi_ws, adj_ws);
    attn4<<<dim3(1024), dim3(64), 0, stream>>>(
        h_ws, azi_ws, azj_ws, adi_ws, adj_ws, a, pacc, pm, ps);
    combine_kernel<<<dim3(1024), dim3(256), 0, stream>>>(
        pacc, pm, ps, bpar, out);
}

// Round 13
// 55.171 us; speedup vs baseline: 1.3193x; 1.3193x over previous
//
#include <hip/hip_runtime.h>
#include <hip/hip_bf16.h>

#define NN 512
#define FIN 128
#define HH 4
#define DD 64
#define SW 68   // permuted/padded e-width: 17 groups x 4
// lrelu(z) = 0.6*z + 0.4*|z|; a.lrelu folded: 0.6*(a.zi+a.zj) + sum_g sgn_g*|azi+azj|

// ws layout (floats):
//  h_ws   [8][512][64]         262144  @ 0
//  azi_ws [8][512][68]         278528  @ 262144
//  azj_ws [8][512][68]         278528  @ 540672
//  adi_ws [8][512]             4096    @ 819200
//  adj_ws [8][512]             4096    @ 823296
//  pacc   [16][8][512][64]     4194304 @ 827392
//  pm     [16][4096]           65536   @ 5021696
//  ps     [16][4096]           65536   @ 5087232

// ---------------------------------------------------------------------------
// proj: unchanged (validated r12). 512 blocks x 256.
// ---------------------------------------------------------------------------
__global__ __launch_bounds__(256) void proj_kernel(
    const float* __restrict__ x, const float* __restrict__ Wp,
    const float* __restrict__ bp, const float* __restrict__ Wc,
    const float* __restrict__ Wcb, const float* __restrict__ a,
    float* __restrict__ h_ws, float* __restrict__ azi_ws, float* __restrict__ azj_ws,
    float* __restrict__ adi_ws, float* __restrict__ adj_ws)
{
    int blk = blockIdx.x;
    int bh = blk >> 6;
    int n0 = (blk & 63) << 3;
    int b = bh >> 2, hh = bh & 3;

    __shared__ float xs[8 * FIN];
    __shared__ float hs[8][DD];
    __shared__ float Wcs[DD][2 * DD + 1];

    int t = threadIdx.x;

    ((float4*)xs)[t] = ((const float4*)(x + ((size_t)b * NN + n0) * FIN))[t];
    {
        const float4* wg = (const float4*)(Wc + (size_t)hh * DD * 2 * DD);
        #pragma unroll
        for (int k = 0; k < 8; ++k) {
            int idx = t + 256 * k;
            int r = idx >> 5, c4 = (idx & 31) * 4;
            float4 v = wg[idx];
            Wcs[r][c4] = v.x; Wcs[r][c4 + 1] = v.y;
            Wcs[r][c4 + 2] = v.z; Wcs[r][c4 + 3] = v.w;
        }
    }
    __syncthreads();

    int e = t & 63, w = t >> 6;            // rows w, w+4
    const float* Wph = Wp + (size_t)hh * FIN * DD;
    float bpv = bp[hh * DD + e];
    float acc0 = bpv, acc1 = bpv;
    #pragma unroll 8
    for (int i = 0; i < FIN; ++i) {
        float wv = Wph[i * DD + e];
        acc0 = fmaf(xs[w * FIN + i], wv, acc0);
        acc1 = fmaf(xs[(w + 4) * FIN + i], wv, acc1);
    }
    hs[w][e] = acc0; hs[w + 4][e] = acc1;
    float* hg = h_ws + ((size_t)bh * NN + n0) * DD;
    hg[w * DD + e] = acc0; hg[(w + 4) * DD + e] = acc1;
    __syncthreads();

    float zb = Wcb[hh * DD + e];
    float zi0 = zb, zi1 = zb, zj0 = 0.f, zj1 = 0.f;
    #pragma unroll 8
    for (int d2 = 0; d2 < DD; ++d2) {
        float w1 = Wcs[e][d2];
        float w2 = Wcs[e][DD + d2];
        float h0 = hs[w][d2], h1 = hs[w + 4][d2];
        zi0 = fmaf(h0, w1, zi0); zi1 = fmaf(h1, w1, zi1);
        zj0 = fmaf(h0, w2, zj0); zj1 = fmaf(h1, w2, zj1);
    }

    float av = a[hh * DD + e];
    float p0 = av * zi0, p1 = av * zi1, q0 = av * zj0, q1 = av * zj1;
    #pragma unroll
    for (int off = 32; off; off >>= 1) {
        p0 += __shfl_xor(p0, off); p1 += __shfl_xor(p1, off);
        q0 += __shfl_xor(q0, off); q1 += __shfl_xor(q1, off);
    }
    if (e == 0) {
        adi_ws[bh * NN + n0 + w]     = 0.6f * p0;
        adi_ws[bh * NN + n0 + w + 4] = 0.6f * p1;
        adj_ws[bh * NN + n0 + w]     = 0.6f * q0;
        adj_ws[bh * NN + n0 + w + 4] = 0.6f * q1;
    }

    unsigned long long mask = __ballot(av >= 0.f);
    int np = __popcll(mask);
    int GP = (np + 3) >> 2;
    int below = __popcll(mask & ((1ull << e) - 1ull));
    int slot = (av >= 0.f) ? below : (4 * GP + (e - below));
    float pav = __builtin_fabsf(av);

    float* azib = azi_ws + ((size_t)bh * NN + n0) * SW;
    float* azjb = azj_ws + ((size_t)bh * NN + n0) * SW;
    azib[w * SW + slot]       = pav * zi0;
    azib[(w + 4) * SW + slot] = pav * zi1;
    azjb[w * SW + slot]       = pav * zj0;
    azjb[(w + 4) * SW + slot] = pav * zj1;
    int p1c = 4 * GP - np;
    if (e < 4) {
        int psl = (e < p1c) ? (np + e) : (4 * GP + 64 - np + (e - p1c));
        azib[w * SW + psl] = 0.f; azib[(w + 4) * SW + psl] = 0.f;
        azjb[w * SW + psl] = 0.f; azjb[(w + 4) * SW + psl] = 0.f;
    }
}

// ---------------------------------------------------------------------------
// attn5: lane = i, [64 i][32 j] per 1-wave block; operands via LDS
// uniform-broadcast (ordered, partial lgkmcnt); in-register softmax (no shfl).
// grid = 8bh x 8is x 16js = 1024 blocks x 64 thr.
// ---------------------------------------------------------------------------
#define AZJ 0        // [32][68] floats
#define HT  2176     // [32][64]
#define ADJ 4224     // [32]
__global__ __launch_bounds__(64) void attn5(
    const float* __restrict__ h_ws, const float* __restrict__ azi_ws,
    const float* __restrict__ azj_ws, const float* __restrict__ adi_ws,
    const float* __restrict__ adj_ws, const float* __restrict__ a,
    float* __restrict__ pacc, float* __restrict__ pm, float* __restrict__ ps)
{
    int blk = blockIdx.x;
    int js = blk & 15, is_ = (blk >> 4) & 7, bh = blk >> 7;
    int i0 = is_ << 6, j0 = js << 5, hh = bh & 3;
    int lane = threadIdx.x;

    __shared__ float smem[64 * 72];    // 18 KB, reused 3 ways

    // ---- phase A: stage azi strip [64][68] -> [64][72], copy own row to regs
    {
        const float4* src = (const float4*)(azi_ws + ((size_t)bh * NN + i0) * SW);
        #pragma unroll
        for (int k = 0; k < 17; ++k) {
            int idx = lane + 64 * k;           // 1088 float4
            int r = idx / 17, c = idx % 17;
            *(float4*)&smem[r * 72 + c * 4] = src[idx];
        }
    }
    __syncthreads();
    float4 azi4[17];
    #pragma unroll
    for (int k = 0; k < 17; ++k)
        azi4[k] = *(const float4*)&smem[lane * 72 + k * 4];
    __syncthreads();

    // ---- phase B: stage azj [32][68] + h [32][64] + adj [32] (coalesced)
    {
        const float4* srcj = (const float4*)(azj_ws + ((size_t)bh * NN + j0) * SW);
        #pragma unroll
        for (int k = 0; k < 9; ++k) {
            int idx = lane + 64 * k;
            if (idx < 544) ((float4*)&smem[AZJ])[idx] = srcj[idx];
        }
        const float4* srch = (const float4*)(h_ws + ((size_t)bh * NN + j0) * DD);
        #pragma unroll
        for (int k = 0; k < 8; ++k)
            ((float4*)&smem[HT])[lane + 64 * k] = srch[lane + 64 * k];
        if (lane < 32) smem[ADJ + lane] = adj_ws[bh * NN + j0 + lane];
    }

    float av_e = a[hh * DD + lane];
    unsigned long long mask = __ballot(av_e >= 0.f);
    int GP = (__popcll(mask) + 3) >> 2;
    float sgn[17];
    #pragma unroll
    for (int k = 0; k < 17; ++k) sgn[k] = (k < GP) ? 0.4f : -0.4f;
    float adiv = adi_ws[bh * NN + i0 + lane];

    __syncthreads();

    // ---- scores: 32 j, pure VALU + uniform b128 broadcast reads ----
    float p[32];
    #pragma unroll
    for (int j = 0; j < 32; ++j) {
        const float4* aj = (const float4*)&smem[AZJ + j * SW];   // uniform
        float c0 = 0.f, c1 = 0.f, c2 = 0.f, c3 = 0.f;
        #pragma unroll
        for (int k = 0; k < 17; ++k) {
            float4 A = aj[k];
            float sg = sgn[k];
            c0 = fmaf(sg, __builtin_fabsf(azi4[k].x + A.x), c0);
            c1 = fmaf(sg, __builtin_fabsf(azi4[k].y + A.y), c1);
            c2 = fmaf(sg, __builtin_fabsf(azi4[k].z + A.z), c2);
            c3 = fmaf(sg, __builtin_fabsf(azi4[k].w + A.w), c3);
        }
        p[j] = adiv + smem[ADJ + j] + ((c0 + c1) + (c2 + c3));
    }

    // ---- in-register softmax partial (no shfl, no LDS) ----
    float m = p[0];
    #pragma unroll
    for (int j = 1; j < 32; ++j) m = fmaxf(m, p[j]);
    float s = 0.f;
    #pragma unroll
    for (int j = 0; j < 32; ++j) { p[j] = __expf(p[j] - m); s += p[j]; }
    pm[js * 4096 + bh * NN + i0 + lane] = m;
    ps[js * 4096 + bh * NN + i0 + lane] = s;

    // ---- PV: acc[64] in regs; h via uniform b128 broadcast ----
    float acc[64];
    #pragma unroll
    for (int d = 0; d < 64; ++d) acc[d] = 0.f;
    #pragma unroll
    for (int j = 0; j < 32; ++j) {
        const float4* hj = (const float4*)&smem[HT + j * DD];    // uniform
        float pj = p[j];
        #pragma unroll
        for (int k = 0; k < 16; ++k) {
            float4 hv = hj[k];
            acc[4 * k + 0] = fmaf(pj, hv.x, acc[4 * k + 0]);
            acc[4 * k + 1] = fmaf(pj, hv.y, acc[4 * k + 1]);
            acc[4 * k + 2] = fmaf(pj, hv.z, acc[4 * k + 2]);
            acc[4 * k + 3] = fmaf(pj, hv.w, acc[4 * k + 3]);
        }
    }

    // ---- epilogue: transpose via LDS (stride 65, conflict-free) ----
    #pragma unroll
    for (int d = 0; d < 64; ++d) smem[lane * 65 + d] = acc[d];
    __syncthreads();
    float* pb = pacc + ((size_t)(js * 8 + bh) * NN + i0) * DD + lane;
    #pragma unroll
    for (int i = 0; i < 64; ++i)
        pb[(size_t)i * DD] = smem[i * 65 + lane];
}

// ---------------------------------------------------------------------------
// combine 16 j-splits + bias (validated r12). grid = 1024 x 256.
// ---------------------------------------------------------------------------
__global__ __launch_bounds__(256) void combine_kernel(
    const float* __restrict__ pacc, const float* __restrict__ pm,
    const float* __restrict__ ps, const float* __restrict__ bias_param,
    float* __restrict__ out)
{
    int tid = blockIdx.x * 256 + threadIdx.x;
    int d = tid & 63;
    int row = tid >> 6;
    int bh = row >> 9, n = row & 511;
    int b = bh >> 2, hh = bh & 3;
    float mv[16];
    float m = -1e30f;
    #pragma unroll
    for (int p = 0; p < 16; ++p) { mv[p] = pm[p * 4096 + row]; m = fmaxf(m, mv[p]); }
    float denom = 0.f, acc = 0.f;
    #pragma unroll
    for (int p = 0; p < 16; ++p) {
        float wgt = __expf(mv[p] - m);
        denom = fmaf(ps[p * 4096 + row], wgt, denom);
        acc = fmaf(pacc[(size_t)p * 262144 + (size_t)row * 64 + d], wgt, acc);
    }
    out[((size_t)b * NN + n) * (HH * DD) + hh * DD + d] =
        acc / denom + bias_param[hh * DD + d];
}

extern "C" void kernel_launch(void* const* d_in, const int* in_sizes, int n_in,
                              void* d_out, int out_size, void* d_ws, size_t ws_size,
                              hipStream_t stream) {
    const float* x    = (const float*)d_in[0];
    const float* Wp   = (const float*)d_in[1];
    const float* bp   = (const float*)d_in[2];
    const float* Wc   = (const float*)d_in[3];
    const float* Wcb  = (const float*)d_in[4];
    const float* a    = (const float*)d_in[5];
    const float* bpar = (const float*)d_in[6];
    float* out = (float*)d_out;

    float* ws     = (float*)d_ws;
    float* h_ws   = ws;
    float* azi_ws = ws + 262144;
    float* azj_ws = ws + 540672;
    float* adi_ws = ws + 819200;
    float* adj_ws = ws + 823296;
    float* pacc   = ws + 827392;
    float* pm     = ws + 5021696;
    float* ps     = ws + 5087232;

    proj_kernel<<<dim3(512), dim3(256), 0, stream>>>(
        x, Wp, bp, Wc, Wcb, a, h_ws, azi_ws, azj_ws, adi_ws, adj_ws);
    attn5<<<dim3(1024), dim3(64), 0, stream>>>(
        h_ws, azi_ws, azj_ws, adi_ws, adj_ws, a, pacc, pm, ps);
    combine_kernel<<<dim3(1024), dim3(256), 0, stream>>>(
        pacc, pm, ps, bpar, out);
}

// Round 14
// 43.984 us; speedup vs baseline: 1.6549x; 1.2543x over previous
//
#include <hip/hip_runtime.h>
#include <hip/hip_bf16.h>

#define NN 512
#define FIN 128
#define HH 4
#define DD 64
#define SW 68   // permuted/padded e-width: 17 groups x 4
// lrelu(z) = 0.6*z + 0.4*|z|; a.lrelu folded: 0.6*(a.zi+a.zj) + sum_g sgn_g*|azi+azj|

// ws layout (floats):
//  h_ws   [8][512][64]         262144  @ 0
//  azi_ws [8][512][68]         278528  @ 262144
//  azj_ws [8][512][68]         278528  @ 540672
//  adi_ws [8][512]             4096    @ 819200
//  adj_ws [8][512]             4096    @ 823296
//  pacc   [16][8][512][64]     4194304 @ 827392
//  pm     [16][4096]           65536   @ 5021696
//  ps     [16][4096]           65536   @ 5087232

// ---------------------------------------------------------------------------
// proj: unchanged (validated r12/r13). 512 blocks x 256.
// ---------------------------------------------------------------------------
__global__ __launch_bounds__(256) void proj_kernel(
    const float* __restrict__ x, const float* __restrict__ Wp,
    const float* __restrict__ bp, const float* __restrict__ Wc,
    const float* __restrict__ Wcb, const float* __restrict__ a,
    float* __restrict__ h_ws, float* __restrict__ azi_ws, float* __restrict__ azj_ws,
    float* __restrict__ adi_ws, float* __restrict__ adj_ws)
{
    int blk = blockIdx.x;
    int bh = blk >> 6;
    int n0 = (blk & 63) << 3;
    int b = bh >> 2, hh = bh & 3;

    __shared__ float xs[8 * FIN];
    __shared__ float hs[8][DD];
    __shared__ float Wcs[DD][2 * DD + 1];

    int t = threadIdx.x;

    ((float4*)xs)[t] = ((const float4*)(x + ((size_t)b * NN + n0) * FIN))[t];
    {
        const float4* wg = (const float4*)(Wc + (size_t)hh * DD * 2 * DD);
        #pragma unroll
        for (int k = 0; k < 8; ++k) {
            int idx = t + 256 * k;
            int r = idx >> 5, c4 = (idx & 31) * 4;
            float4 v = wg[idx];
            Wcs[r][c4] = v.x; Wcs[r][c4 + 1] = v.y;
            Wcs[r][c4 + 2] = v.z; Wcs[r][c4 + 3] = v.w;
        }
    }
    __syncthreads();

    int e = t & 63, w = t >> 6;            // rows w, w+4
    const float* Wph = Wp + (size_t)hh * FIN * DD;
    float bpv = bp[hh * DD + e];
    float acc0 = bpv, acc1 = bpv;
    #pragma unroll 8
    for (int i = 0; i < FIN; ++i) {
        float wv = Wph[i * DD + e];
        acc0 = fmaf(xs[w * FIN + i], wv, acc0);
        acc1 = fmaf(xs[(w + 4) * FIN + i], wv, acc1);
    }
    hs[w][e] = acc0; hs[w + 4][e] = acc1;
    float* hg = h_ws + ((size_t)bh * NN + n0) * DD;
    hg[w * DD + e] = acc0; hg[(w + 4) * DD + e] = acc1;
    __syncthreads();

    float zb = Wcb[hh * DD + e];
    float zi0 = zb, zi1 = zb, zj0 = 0.f, zj1 = 0.f;
    #pragma unroll 8
    for (int d2 = 0; d2 < DD; ++d2) {
        float w1 = Wcs[e][d2];
        float w2 = Wcs[e][DD + d2];
        float h0 = hs[w][d2], h1 = hs[w + 4][d2];
        zi0 = fmaf(h0, w1, zi0); zi1 = fmaf(h1, w1, zi1);
        zj0 = fmaf(h0, w2, zj0); zj1 = fmaf(h1, w2, zj1);
    }

    float av = a[hh * DD + e];
    float p0 = av * zi0, p1 = av * zi1, q0 = av * zj0, q1 = av * zj1;
    #pragma unroll
    for (int off = 32; off; off >>= 1) {
        p0 += __shfl_xor(p0, off); p1 += __shfl_xor(p1, off);
        q0 += __shfl_xor(q0, off); q1 += __shfl_xor(q1, off);
    }
    if (e == 0) {
        adi_ws[bh * NN + n0 + w]     = 0.6f * p0;
        adi_ws[bh * NN + n0 + w + 4] = 0.6f * p1;
        adj_ws[bh * NN + n0 + w]     = 0.6f * q0;
        adj_ws[bh * NN + n0 + w + 4] = 0.6f * q1;
    }

    unsigned long long mask = __ballot(av >= 0.f);
    int np = __popcll(mask);
    int GP = (np + 3) >> 2;
    int below = __popcll(mask & ((1ull << e) - 1ull));
    int slot = (av >= 0.f) ? below : (4 * GP + (e - below));
    float pav = __builtin_fabsf(av);

    float* azib = azi_ws + ((size_t)bh * NN + n0) * SW;
    float* azjb = azj_ws + ((size_t)bh * NN + n0) * SW;
    azib[w * SW + slot]       = pav * zi0;
    azib[(w + 4) * SW + slot] = pav * zi1;
    azjb[w * SW + slot]       = pav * zj0;
    azjb[(w + 4) * SW + slot] = pav * zj1;
    int p1c = 4 * GP - np;
    if (e < 4) {
        int psl = (e < p1c) ? (np + e) : (4 * GP + 64 - np + (e - p1c));
        azib[w * SW + psl] = 0.f; azib[(w + 4) * SW + psl] = 0.f;
        azjb[w * SW + psl] = 0.f; azjb[(w + 4) * SW + psl] = 0.f;
    }
}

// ---------------------------------------------------------------------------
// attn6: [64 i][32 j] per 256-thr block. Phase1 scores lane=i (azi in regs,
// azj uniform b128); Phase2 softmax 4 lanes/row (2 shfl); Phase3 PV lane=d
// (acc[16] regs, p via uniform b128). grid = 8bh x 8is x 16js = 1024 blocks.
// ---------------------------------------------------------------------------
#define AZJ 0        // [32][68] floats in smA
#define HT  2176     // [32][64]
#define ADJ 4224     // [32]
__global__ __launch_bounds__(256) void attn6(
    const float* __restrict__ h_ws, const float* __restrict__ azi_ws,
    const float* __restrict__ azj_ws, const float* __restrict__ adi_ws,
    const float* __restrict__ adj_ws, const float* __restrict__ a,
    float* __restrict__ pacc, float* __restrict__ pm, float* __restrict__ ps)
{
    int blk = blockIdx.x;
    int js = blk & 15, is_ = (blk >> 4) & 7, bh = blk >> 7;
    int i0 = is_ << 6, j0 = js << 5, hh = bh & 3;
    int t = threadIdx.x, lane = t & 63, w = t >> 6;

    __shared__ float smA[64 * 68];   // 17.4 KB: azi staging, then azj+h+adj
    __shared__ float eP[32 * 68];    // 8.7 KB: e then p, [j][i(+pad)]

    // ---- stage azi strip [64][68] (coalesced), then own row -> regs ----
    {
        const float4* src = (const float4*)(azi_ws + ((size_t)bh * NN + i0) * SW);
        float4* dst = (float4*)smA;
        #pragma unroll
        for (int k = 0; k < 5; ++k) {
            int idx = t + 256 * k;
            if (idx < 1088) dst[idx] = src[idx];
        }
    }
    __syncthreads();
    float4 azi4[17];
    #pragma unroll
    for (int k = 0; k < 17; ++k)
        azi4[k] = *(const float4*)&smA[lane * SW + 4 * k];
    float adiv = adi_ws[bh * NN + i0 + lane];
    __syncthreads();                 // azi staging region free

    // ---- stage azj [32][68] + h [32][64] + adj [32] (coalesced) ----
    {
        const float4* sj = (const float4*)(azj_ws + ((size_t)bh * NN + j0) * SW);
        #pragma unroll
        for (int k = 0; k < 3; ++k) {
            int idx = t + 256 * k;
            if (idx < 544) ((float4*)&smA[AZJ])[idx] = sj[idx];
        }
        const float4* sh = (const float4*)(h_ws + ((size_t)bh * NN + j0) * DD);
        ((float4*)&smA[HT])[t]       = sh[t];
        ((float4*)&smA[HT])[t + 256] = sh[t + 256];
        if (t < 32) smA[ADJ + t] = adj_ws[bh * NN + j0 + t];
    }

    float av_e = a[hh * DD + lane];
    unsigned long long mask = __ballot(av_e >= 0.f);
    int GP = (__popcll(mask) + 3) >> 2;

    __syncthreads();

    // ---- phase 1: scores. wave w does j = 8w..8w+7, lane = i ----
    #pragma unroll
    for (int jj = 0; jj < 8; ++jj) {
        int j = 8 * w + jj;
        const float4* aj = (const float4*)&smA[AZJ + j * SW];   // uniform
        float adjv = smA[ADJ + j];                              // uniform
        float c0 = 0.f, c1 = 0.f, c2 = 0.f, c3 = 0.f;
        #pragma unroll
        for (int k = 0; k < 17; ++k) {
            float4 A = aj[k];
            float sg = (k < GP) ? 0.4f : -0.4f;
            c0 = fmaf(sg, __builtin_fabsf(azi4[k].x + A.x), c0);
            c1 = fmaf(sg, __builtin_fabsf(azi4[k].y + A.y), c1);
            c2 = fmaf(sg, __builtin_fabsf(azi4[k].z + A.z), c2);
            c3 = fmaf(sg, __builtin_fabsf(azi4[k].w + A.w), c3);
        }
        eP[j * SW + lane] = adiv + adjv + ((c0 + c1) + (c2 + c3));
    }
    __syncthreads();

    // ---- phase 2: softmax. lane (il, jq): row iL = 16w + il, 8 j each ----
    {
        int il = lane & 15, jq = lane >> 4;
        int iL = 16 * w + il;
        float e8[8];
        float m = -1e30f;
        #pragma unroll
        for (int jj = 0; jj < 8; ++jj) {
            e8[jj] = eP[(jq * 8 + jj) * SW + iL];
            m = fmaxf(m, e8[jj]);
        }
        m = fmaxf(m, __shfl_xor(m, 16));
        m = fmaxf(m, __shfl_xor(m, 32));
        float s = 0.f;
        #pragma unroll
        for (int jj = 0; jj < 8; ++jj) {
            float p = __expf(e8[jj] - m);
            s += p;
            eP[(jq * 8 + jj) * SW + iL] = p;
        }
        s += __shfl_xor(s, 16);
        s += __shfl_xor(s, 32);
        if (jq == 0) {
            pm[js * 4096 + bh * NN + i0 + iL] = m;
            ps[js * 4096 + bh * NN + i0 + iL] = s;
        }
    }
    __syncthreads();

    // ---- phase 3: PV. wave w: i = 16w..16w+15, lane = d, acc[16] regs ----
    float acc[16];
    #pragma unroll
    for (int ii = 0; ii < 16; ++ii) acc[ii] = 0.f;
    #pragma unroll 8
    for (int j = 0; j < 32; ++j) {
        float hv = smA[HT + j * 64 + lane];                     // per-lane b32
        const float4* pp = (const float4*)&eP[j * SW + 16 * w]; // uniform b128
        float4 p0 = pp[0], p1 = pp[1], p2 = pp[2], p3 = pp[3];
        acc[0]  = fmaf(p0.x, hv, acc[0]);  acc[1]  = fmaf(p0.y, hv, acc[1]);
        acc[2]  = fmaf(p0.z, hv, acc[2]);  acc[3]  = fmaf(p0.w, hv, acc[3]);
        acc[4]  = fmaf(p1.x, hv, acc[4]);  acc[5]  = fmaf(p1.y, hv, acc[5]);
        acc[6]  = fmaf(p1.z, hv, acc[6]);  acc[7]  = fmaf(p1.w, hv, acc[7]);
        acc[8]  = fmaf(p2.x, hv, acc[8]);  acc[9]  = fmaf(p2.y, hv, acc[9]);
        acc[10] = fmaf(p2.z, hv, acc[10]); acc[11] = fmaf(p2.w, hv, acc[11]);
        acc[12] = fmaf(p3.x, hv, acc[12]); acc[13] = fmaf(p3.y, hv, acc[13]);
        acc[14] = fmaf(p3.z, hv, acc[14]); acc[15] = fmaf(p3.w, hv, acc[15]);
    }

    // ---- store partials (coalesced: lane = d) ----
    float* pb = pacc + ((size_t)(js * 8 + bh) * NN + i0 + 16 * w) * DD + lane;
    #pragma unroll
    for (int ii = 0; ii < 16; ++ii)
        pb[(size_t)ii * DD] = acc[ii];
}

// ---------------------------------------------------------------------------
// combine 16 j-splits + bias (validated r12/r13). grid = 1024 x 256.
// ---------------------------------------------------------------------------
__global__ __launch_bounds__(256) void combine_kernel(
    const float* __restrict__ pacc, const float* __restrict__ pm,
    const float* __restrict__ ps, const float* __restrict__ bias_param,
    float* __restrict__ out)
{
    int tid = blockIdx.x * 256 + threadIdx.x;
    int d = tid & 63;
    int row = tid >> 6;
    int bh = row >> 9, n = row & 511;
    int b = bh >> 2, hh = bh & 3;
    float mv[16];
    float m = -1e30f;
    #pragma unroll
    for (int p = 0; p < 16; ++p) { mv[p] = pm[p * 4096 + row]; m = fmaxf(m, mv[p]); }
    float denom = 0.f, acc = 0.f;
    #pragma unroll
    for (int p = 0; p < 16; ++p) {
        float wgt = __expf(mv[p] - m);
        denom = fmaf(ps[p * 4096 + row], wgt, denom);
        acc = fmaf(pacc[(size_t)p * 262144 + (size_t)row * 64 + d], wgt, acc);
    }
    out[((size_t)b * NN + n) * (HH * DD) + hh * DD + d] =
        acc / denom + bias_param[hh * DD + d];
}

extern "C" void kernel_launch(void* const* d_in, const int* in_sizes, int n_in,
                              void* d_out, int out_size, void* d_ws, size_t ws_size,
                              hipStream_t stream) {
    const float* x    = (const float*)d_in[0];
    const float* Wp   = (const float*)d_in[1];
    const float* bp   = (const float*)d_in[2];
    const float* Wc   = (const float*)d_in[3];
    const float* Wcb  = (const float*)d_in[4];
    const float* a    = (const float*)d_in[5];
    const float* bpar = (const float*)d_in[6];
    float* out = (float*)d_out;

    float* ws     = (float*)d_ws;
    float* h_ws   = ws;
    float* azi_ws = ws + 262144;
    float* azj_ws = ws + 540672;
    float* adi_ws = ws + 819200;
    float* adj_ws = ws + 823296;
    float* pacc   = ws + 827392;
    float* pm     = ws + 5021696;
    float* ps     = ws + 5087232;

    proj_kernel<<<dim3(512), dim3(256), 0, stream>>>(
        x, Wp, bp, Wc, Wcb, a, h_ws, azi_ws, azj_ws, adi_ws, adj_ws);
    attn6<<<dim3(1024), dim3(256), 0, stream>>>(
        h_ws, azi_ws, azj_ws, adi_ws, adj_ws, a, pacc, pm, ps);
    combine_kernel<<<dim3(1024), dim3(256), 0, stream>>>(
        pacc, pm, ps, bpar, out);
}